// Round 9
// baseline (1184.628 us; speedup 1.0000x reference)
//
#include <hip/hip_runtime.h>
#include <hip/hip_fp16.h>

// GCN: fully fused single-launch kernel, software grid barriers (load-poll).
// Phases: [init+Wsplit+p1] | p2 | 3x(gemm | agg) | pool   -> 7 barriers.
#define NN 10000
#define NE 640000
#define NG 64
#define CAP 128   // slot capacity per dst (slot deg holds zero-row pad)
#define NB 625    // buckets of 16 dst nodes
#define BCAP 1280 // per-bucket edge capacity
#define GRIDSZ 1024
#define NBAR 8

typedef _Float16 f16x8 __attribute__((ext_vector_type(8)));
typedef float f32x4 __attribute__((ext_vector_type(4)));

union ShMem {
    int hist[NB];                                  // p1
    struct { int buf[16 * CAP]; int cnt[16]; } p2; // p2
    float sm[256];                                 // pool
};

// Grid barrier: arrival = one device-scope RMW per block; poll = atomic LOADS
// (no ownership transfer -> no contention with arrivals). Fresh slot per barrier,
// zeroed host-side each launch. threadfence = release/acquire for plain ld/st.
__device__ __forceinline__ void gsync(int* bar, int id) {
    __syncthreads();
    if (threadIdx.x == 0) {
        __threadfence();  // release my block's writes
        atomicAdd(&bar[id], 1);
        while (__hip_atomic_load(&bar[id], __ATOMIC_RELAXED, __HIP_MEMORY_SCOPE_AGENT) < GRIDSZ)
            __builtin_amdgcn_s_sleep(8);
        __threadfence();  // acquire others' writes
    }
    __syncthreads();
}

// ---------------- GEMM phase (MFMA, split fp16) ----------------
// g16[r][c] = fp16( dis[r] * (act(in)[r] @ W)[:,c] ); rows 10000..10015 zero pad.
__device__ __forceinline__ void gemm_phase(const float* __restrict__ in,
                                           const __half* __restrict__ whT,
                                           const __half* __restrict__ wlT,
                                           const int* __restrict__ deg,
                                           __half* __restrict__ g16, int relu,
                                           int bid, int t) {
    const _Float16* wh = (const _Float16*)whT;
    const _Float16* wl = (const _Float16*)wlT;
    for (int s = bid; s < 626; s += GRIDSZ) {
        int w = t >> 6, l = t & 63;
        int rw = (s % 313) * 32 + (w & 1) * 16;
        int cw = (s / 313) * 64 + (w >> 1) * 32;
        int lr = l & 15, lg = l >> 4;
        int row = rw + lr;
        int rclamp = min(row, NN - 1);
        f32x4 acc0 = {0.f, 0.f, 0.f, 0.f}, acc1 = {0.f, 0.f, 0.f, 0.f};
#pragma unroll
        for (int ks = 0; ks < 4; ks++) {
            int kb = ks * 32 + lg * 8;
            float4 xa = *(const float4*)&in[rclamp * 128 + kb];
            float4 xb = *(const float4*)&in[rclamp * 128 + kb + 4];
            float x0 = xa.x, x1 = xa.y, x2 = xa.z, x3 = xa.w;
            float x4 = xb.x, x5 = xb.y, x6 = xb.z, x7 = xb.w;
            if (relu) {
                x0 = fmaxf(x0, 0.f); x1 = fmaxf(x1, 0.f); x2 = fmaxf(x2, 0.f); x3 = fmaxf(x3, 0.f);
                x4 = fmaxf(x4, 0.f); x5 = fmaxf(x5, 0.f); x6 = fmaxf(x6, 0.f); x7 = fmaxf(x7, 0.f);
            }
            f16x8 ah, al;
            ah[0] = (_Float16)x0; al[0] = (_Float16)(x0 - (float)ah[0]);
            ah[1] = (_Float16)x1; al[1] = (_Float16)(x1 - (float)ah[1]);
            ah[2] = (_Float16)x2; al[2] = (_Float16)(x2 - (float)ah[2]);
            ah[3] = (_Float16)x3; al[3] = (_Float16)(x3 - (float)ah[3]);
            ah[4] = (_Float16)x4; al[4] = (_Float16)(x4 - (float)ah[4]);
            ah[5] = (_Float16)x5; al[5] = (_Float16)(x5 - (float)ah[5]);
            ah[6] = (_Float16)x6; al[6] = (_Float16)(x6 - (float)ah[6]);
            ah[7] = (_Float16)x7; al[7] = (_Float16)(x7 - (float)ah[7]);
            int c0 = cw + lr;
            f16x8 bh0 = *(const f16x8*)&wh[c0 * 128 + kb];
            f16x8 bl0 = *(const f16x8*)&wl[c0 * 128 + kb];
            f16x8 bh1 = *(const f16x8*)&wh[(c0 + 16) * 128 + kb];
            f16x8 bl1 = *(const f16x8*)&wl[(c0 + 16) * 128 + kb];
            acc0 = __builtin_amdgcn_mfma_f32_16x16x32_f16(ah, bh0, acc0, 0, 0, 0);
            acc1 = __builtin_amdgcn_mfma_f32_16x16x32_f16(ah, bh1, acc1, 0, 0, 0);
            acc0 = __builtin_amdgcn_mfma_f32_16x16x32_f16(al, bh0, acc0, 0, 0, 0);
            acc1 = __builtin_amdgcn_mfma_f32_16x16x32_f16(al, bh1, acc1, 0, 0, 0);
            acc0 = __builtin_amdgcn_mfma_f32_16x16x32_f16(ah, bl0, acc0, 0, 0, 0);
            acc1 = __builtin_amdgcn_mfma_f32_16x16x32_f16(ah, bl1, acc1, 0, 0, 0);
        }
#pragma unroll
        for (int reg = 0; reg < 4; reg++) {
            int r = rw + lg * 4 + reg;
            int c = cw + lr;
            if (r < NN) {
                float d = rsqrtf((float)deg[r] + 1.0f);
                g16[r * 128 + c] = __float2half(acc0[reg] * d);
                g16[r * 128 + c + 16] = __float2half(acc1[reg] * d);
            } else {  // zero pad rows 10000..10015
                g16[r * 128 + c] = __float2half(0.f);
                g16[r * 128 + c + 16] = __float2half(0.f);
            }
        }
    }
}

// ---------------- aggregation phase: dual-edge half-wave ----------------
__device__ __forceinline__ void accp(uint2 v, float2& p, float2& q) {
    float2 f0 = __half22float2(*(__half2*)&v.x);
    float2 f1 = __half22float2(*(__half2*)&v.y);
    p.x += f0.x; p.y += f0.y; q.x += f1.x; q.y += f1.y;
}

__device__ __forceinline__ void agg_phase(const __half* __restrict__ g16,
                                          const float* __restrict__ bias,
                                          const int* __restrict__ deg,
                                          const int* __restrict__ csrc,
                                          float* __restrict__ out,
                                          int bid, int t) {
    int w = t >> 6, l = t & 63;
    int half = l >> 5, li = l & 31;
    int co = li * 4;  // column offset in halfs
    for (int i = bid * 4 + w; i < NN; i += GRIDSZ * 4) {
        int dgi = __builtin_amdgcn_readfirstlane(deg[i]);
        int n = min(dgi, CAP - 1);
        int np = (n + 1) & ~1;  // even; slot n = pad when n odd
        float2 A0 = {0.f, 0.f}, A1 = {0.f, 0.f};
        float2 B0 = {0.f, 0.f}, B1 = {0.f, 0.f};
        if (half == 0) {  // self contribution
            uint2 sv = *(const uint2*)&g16[i * 128 + co];
            float2 f0 = __half22float2(*(__half2*)&sv.x);
            float2 f1 = __half22float2(*(__half2*)&sv.y);
            A0 = f0; A1 = f1;
        }
        const int* cp = &csrc[i << 7];
        for (int base = 0; base < np; base += 64) {
            int m = np - base;
            if (m > 64) m = 64;  // even
            int myedge = (l < m) ? cp[base + l] : NN;
            int pairs = m >> 1;
            int j = 0;
            for (; j + 8 <= pairs; j += 8) {
                int r0 = __shfl(myedge, 2 * j + half);
                int r1 = __shfl(myedge, 2 * j + 2 + half);
                int r2 = __shfl(myedge, 2 * j + 4 + half);
                int r3 = __shfl(myedge, 2 * j + 6 + half);
                int r4 = __shfl(myedge, 2 * j + 8 + half);
                int r5 = __shfl(myedge, 2 * j + 10 + half);
                int r6 = __shfl(myedge, 2 * j + 12 + half);
                int r7 = __shfl(myedge, 2 * j + 14 + half);
                uint2 v0 = *(const uint2*)&g16[r0 * 128 + co];
                uint2 v1 = *(const uint2*)&g16[r1 * 128 + co];
                uint2 v2 = *(const uint2*)&g16[r2 * 128 + co];
                uint2 v3 = *(const uint2*)&g16[r3 * 128 + co];
                uint2 v4 = *(const uint2*)&g16[r4 * 128 + co];
                uint2 v5 = *(const uint2*)&g16[r5 * 128 + co];
                uint2 v6 = *(const uint2*)&g16[r6 * 128 + co];
                uint2 v7 = *(const uint2*)&g16[r7 * 128 + co];
                accp(v0, A0, A1); accp(v1, B0, B1);
                accp(v2, A0, A1); accp(v3, B0, B1);
                accp(v4, A0, A1); accp(v5, B0, B1);
                accp(v6, A0, A1); accp(v7, B0, B1);
            }
            for (; j < pairs; j++) {
                int r = __shfl(myedge, 2 * j + half);
                uint2 v = *(const uint2*)&g16[r * 128 + co];
                accp(v, A0, A1);
            }
        }
        A0.x += B0.x; A0.y += B0.y; A1.x += B1.x; A1.y += B1.y;
        A0.x += __shfl_xor(A0.x, 32);
        A0.y += __shfl_xor(A0.y, 32);
        A1.x += __shfl_xor(A1.x, 32);
        A1.y += __shfl_xor(A1.y, 32);
        if (half == 0) {
            float di = rsqrtf((float)dgi + 1.0f);
            float4 bb = *(const float4*)&bias[co];
            float4 o;
            o.x = di * A0.x + bb.x;
            o.y = di * A0.y + bb.y;
            o.z = di * A1.x + bb.z;
            o.w = di * A1.y + bb.w;
            *(float4*)&out[i * 128 + co] = o;
        }
    }
}

// ---------------- the fused kernel ----------------
__global__ __launch_bounds__(256, 4) void k_fused(
    const float* __restrict__ x, const int* __restrict__ ei, const int* __restrict__ batch,
    const float* __restrict__ W0, const float* __restrict__ b0,
    const float* __restrict__ W1, const float* __restrict__ b1,
    const float* __restrict__ W2, const float* __restrict__ b2,
    float* __restrict__ out,
    int* deg, int* gstart, int* bcur, int* bar, int* csrc, __half* g16, float* abuf,
    int* pk, __half* wh, __half* wl)
{
    __shared__ ShMem sh;
    int bid = blockIdx.x, t = threadIdx.x;

    // ---- phase AB: gstart scan | W split | p1 coarse-bin (independent sub-jobs) ----
    if (bid < 40) {
        int i = bid * 256 + t;
        if (i < NN) {
            int b = batch[i];
            int prev = (i == 0) ? -1 : batch[i - 1];
            for (int g = prev + 1; g <= b; g++) gstart[g] = i;
            if (i == NN - 1)
                for (int g = b + 1; g <= NG; g++) gstart[g] = NN;
        }
    } else if (bid < 232) {
        int wid = bid - 40;             // 0..191
        int z = wid >> 6;               // which W
        int q = (wid & 63) * 256 + t;   // 0..16383
        int c = q >> 7, k = q & 127;
        const float* W = (z == 0) ? W0 : (z == 1) ? W1 : W2;
        float v = W[k * 128 + c];
        __half h = __float2half(v);
        __half lo = __float2half(v - __half2float(h));
        wh[z * 16384 + c * 128 + k] = h;   // transposed [c][k]
        wl[z * 16384 + c * 128 + k] = lo;
    } else if (bid < 389) {
        // p1: bins edges into pk[bucket*BCAP + slot] = src | ((dst&15)<<14)
        for (int q = t; q < NB; q += 256) sh.hist[q] = 0;
        __syncthreads();
        int4 s4[4], d4[4];
        int ebase = (bid - 232) * 4096;
#pragma unroll
        for (int q = 0; q < 4; q++) {
            int e = ebase + q * 1024 + t * 4;
            if (e < NE) {
                s4[q] = *(const int4*)&ei[e];
                d4[q] = *(const int4*)&ei[NE + e];
                atomicAdd(&sh.hist[d4[q].x >> 4], 1);
                atomicAdd(&sh.hist[d4[q].y >> 4], 1);
                atomicAdd(&sh.hist[d4[q].z >> 4], 1);
                atomicAdd(&sh.hist[d4[q].w >> 4], 1);
            }
        }
        __syncthreads();
        for (int q = t; q < NB; q += 256) {
            int h = sh.hist[q];
            sh.hist[q] = (h > 0) ? atomicAdd(&bcur[q], h) : 0;
        }
        __syncthreads();
#pragma unroll
        for (int q = 0; q < 4; q++) {
            int e = ebase + q * 1024 + t * 4;
            if (e < NE) {
                int b0i = d4[q].x >> 4, b1i = d4[q].y >> 4, b2i = d4[q].z >> 4, b3i = d4[q].w >> 4;
                int r0 = atomicAdd(&sh.hist[b0i], 1);
                int r1 = atomicAdd(&sh.hist[b1i], 1);
                int r2 = atomicAdd(&sh.hist[b2i], 1);
                int r3 = atomicAdd(&sh.hist[b3i], 1);
                if (r0 < BCAP) pk[b0i * BCAP + r0] = s4[q].x | ((d4[q].x & 15) << 14);
                if (r1 < BCAP) pk[b1i * BCAP + r1] = s4[q].y | ((d4[q].y & 15) << 14);
                if (r2 < BCAP) pk[b2i * BCAP + r2] = s4[q].z | ((d4[q].z & 15) << 14);
                if (r3 < BCAP) pk[b3i * BCAP + r3] = s4[q].w | ((d4[q].w & 15) << 14);
            }
        }
    }
    gsync(bar, 0);

    // ---- phase C: p2 fine CSR (blocks 0..624) ----
    if (bid < NB) {
        if (t < 16) sh.p2.cnt[t] = 0;
        __syncthreads();
        int n = bcur[bid];
        if (n > BCAP) n = BCAP;
        const int* pb = &pk[bid * BCAP];
        for (int i = t; i < n; i += 256) {
            int v = pb[i];
            int nd = v >> 14;
            int slot = atomicAdd(&sh.p2.cnt[nd], 1);
            if (slot < CAP) sh.p2.buf[(nd << 7) + slot] = v & 0x3FFF;
        }
        __syncthreads();
        int node0 = bid << 4;
        if (t < 16) {
            int c = sh.p2.cnt[t];
            deg[node0 + t] = c;
            sh.p2.buf[(t << 7) + min(c, CAP - 1)] = NN;  // pad -> zero row
        }
        __syncthreads();
        int4* d4 = (int4*)&csrc[node0 << 7];
        const int4* s4 = (const int4*)sh.p2.buf;
#pragma unroll
        for (int i = 0; i < 2; i++) d4[t + i * 256] = s4[t + i * 256];
    }
    gsync(bar, 1);

    // ---- layers ----
    gemm_phase(x, wh, wl, deg, g16, 0, bid, t);
    gsync(bar, 2);
    agg_phase(g16, b0, deg, csrc, abuf, bid, t);
    gsync(bar, 3);
    gemm_phase(abuf, wh + 16384, wl + 16384, deg, g16, 1, bid, t);
    gsync(bar, 4);
    agg_phase(g16, b1, deg, csrc, abuf, bid, t);
    gsync(bar, 5);
    gemm_phase(abuf, wh + 32768, wl + 32768, deg, g16, 1, bid, t);
    gsync(bar, 6);
    agg_phase(g16, b2, deg, csrc, abuf, bid, t);
    gsync(bar, 7);

    // ---- tail: mean pool (blocks 0..63) ----
    if (bid < NG) {
        int g = bid;
        int s = gstart[g], e = gstart[g + 1];
        int c = t & 127, hf = t >> 7;
        float acc = 0.f;
        for (int n = s + hf; n < e; n += 2) acc += abuf[n * 128 + c];
        sh.sm[t] = acc;
        __syncthreads();
        if (hf == 0) {
            float cnt = (float)max(e - s, 1);
            out[g * 128 + c] = (sh.sm[c] + sh.sm[128 + c]) / cnt;
        }
    }
}

extern "C" void kernel_launch(void* const* d_in, const int* in_sizes, int n_in,
                              void* d_out, int out_size, void* d_ws, size_t ws_size,
                              hipStream_t stream) {
    const float* x     = (const float*)d_in[0];
    const int*   ei    = (const int*)d_in[1];
    const int*   batch = (const int*)d_in[2];
    const float* W0 = (const float*)d_in[3];
    const float* b0 = (const float*)d_in[4];
    const float* W1 = (const float*)d_in[5];
    const float* b1 = (const float*)d_in[6];
    const float* W2 = (const float*)d_in[7];
    const float* b2 = (const float*)d_in[8];
    float* out = (float*)d_out;

    // workspace layout (float units)
    float* ws    = (float*)d_ws;
    int*   deg   = (int*)ws;                   // 10000 ints
    int*   gstart= (int*)(ws + 10240);         // 65 ints
    int*   bar   = (int*)(ws + 10320);         // 16 ints (8 used) -- memset'd with bcur
    int*   bcur  = (int*)(ws + 10336);         // 625 ints         -- memset'd
    int*   csrc  = (int*)(ws + 10976);         // 10000*128 ints (5.12 MB)
    __half* g16  = (__half*)(ws + 1290976);    // 10016*128 fp16 (incl. 16 zero pad rows)
    float* abuf  = ws + 1932000;               // 10000*128 f32 (5.12 MB)
    int*   pk    = (int*)(ws + 1932000);       // NB*BCAP ints (3.2 MB) — aliases abuf (dead before agg0)
    __half* wh   = (__half*)(ws + 3212000);    // 3*128*128 fp16 hi, [c][k]
    __half* wlo  = (__half*)(ws + 3236576);    // 3*128*128 fp16 lo

    hipMemsetAsync(ws + 10320, 0, (16 + 625) * sizeof(int), stream);  // bar + bcur
    k_fused<<<GRIDSZ, 256, 0, stream>>>(
        x, ei, batch, W0, b0, W1, b1, W2, b2, out,
        deg, gstart, bcur, bar, csrc, g16, abuf, pk, wh, wlo);
}

// Round 10
// 1008.296 us; speedup vs baseline: 1.1749x; 1.1749x over previous
//
#include <hip/hip_runtime.h>
#include <hip/hip_fp16.h>

// GCN: fully fused single-launch kernel; flag-array grid barriers (no same-line RMW).
// Phases: [init+Wsplit+p1] | p2 | 3x(gemm | agg) | pool   -> 8 barriers.
#define NN 10000
#define NE 640000
#define NG 64
#define CAP 128   // slot capacity per dst (slot deg holds zero-row pad)
#define NB 625    // buckets of 16 dst nodes
#define BCAP 1280 // per-bucket edge capacity
#define GRIDSZ 1024

typedef _Float16 f16x8 __attribute__((ext_vector_type(8)));
typedef float f32x4 __attribute__((ext_vector_type(4)));

union ShMem {
    int hist[NB];                                  // p1
    struct { int buf[16 * CAP]; int cnt[16]; } p2; // p2
    float sm[256];                                 // pool
};

// Grid barrier, epoch-based:
//  arrival  : one atomic STORE per block to its own flags[bid] (pipelined, no RMW chain)
//  detect   : block 0's 256 threads poll 4 flags each, __syncthreads_and
//  release  : block 0 store-releases single `go`; others poll it (reads don't serialize)
// flags/go zeroed host-side per launch; epochs monotonic so no reset between barriers.
__device__ __forceinline__ void gsync(int* flags, int* go, int id, int bid, int t) {
    int epoch = id + 1;
    __syncthreads();
    if (t == 0) {
        __threadfence();  // release this block's writes
        __hip_atomic_store(&flags[bid], epoch, __ATOMIC_RELEASE, __HIP_MEMORY_SCOPE_AGENT);
    }
    if (bid == 0) {
        for (;;) {
            int ok = 1;
#pragma unroll
            for (int q = 0; q < 4; q++) {
                int v = __hip_atomic_load(&flags[t * 4 + q], __ATOMIC_RELAXED,
                                          __HIP_MEMORY_SCOPE_AGENT);
                ok &= (v >= epoch);
            }
            if (__syncthreads_and(ok)) break;
            __builtin_amdgcn_s_sleep(2);
        }
        if (t == 0)
            __hip_atomic_store(go, epoch, __ATOMIC_RELEASE, __HIP_MEMORY_SCOPE_AGENT);
    } else {
        if (t == 0) {
            while (__hip_atomic_load(go, __ATOMIC_RELAXED, __HIP_MEMORY_SCOPE_AGENT) < epoch)
                __builtin_amdgcn_s_sleep(2);
        }
        __syncthreads();
    }
    __threadfence();  // acquire remote writes
}

// ---------------- GEMM phase (MFMA, split fp16) ----------------
// g16[r][c] = fp16( dis[r] * (act(in)[r] @ W)[:,c] ); rows 10000..10015 zero pad.
__device__ __forceinline__ void gemm_phase(const float* __restrict__ in,
                                           const __half* __restrict__ whT,
                                           const __half* __restrict__ wlT,
                                           const int* __restrict__ deg,
                                           __half* __restrict__ g16, int relu,
                                           int bid, int t) {
    const _Float16* wh = (const _Float16*)whT;
    const _Float16* wl = (const _Float16*)wlT;
    for (int s = bid; s < 626; s += GRIDSZ) {
        int w = t >> 6, l = t & 63;
        int rw = (s % 313) * 32 + (w & 1) * 16;
        int cw = (s / 313) * 64 + (w >> 1) * 32;
        int lr = l & 15, lg = l >> 4;
        int row = rw + lr;
        int rclamp = min(row, NN - 1);
        f32x4 acc0 = {0.f, 0.f, 0.f, 0.f}, acc1 = {0.f, 0.f, 0.f, 0.f};
#pragma unroll
        for (int ks = 0; ks < 4; ks++) {
            int kb = ks * 32 + lg * 8;
            float4 xa = *(const float4*)&in[rclamp * 128 + kb];
            float4 xb = *(const float4*)&in[rclamp * 128 + kb + 4];
            float x0 = xa.x, x1 = xa.y, x2 = xa.z, x3 = xa.w;
            float x4 = xb.x, x5 = xb.y, x6 = xb.z, x7 = xb.w;
            if (relu) {
                x0 = fmaxf(x0, 0.f); x1 = fmaxf(x1, 0.f); x2 = fmaxf(x2, 0.f); x3 = fmaxf(x3, 0.f);
                x4 = fmaxf(x4, 0.f); x5 = fmaxf(x5, 0.f); x6 = fmaxf(x6, 0.f); x7 = fmaxf(x7, 0.f);
            }
            f16x8 ah, al;
            ah[0] = (_Float16)x0; al[0] = (_Float16)(x0 - (float)ah[0]);
            ah[1] = (_Float16)x1; al[1] = (_Float16)(x1 - (float)ah[1]);
            ah[2] = (_Float16)x2; al[2] = (_Float16)(x2 - (float)ah[2]);
            ah[3] = (_Float16)x3; al[3] = (_Float16)(x3 - (float)ah[3]);
            ah[4] = (_Float16)x4; al[4] = (_Float16)(x4 - (float)ah[4]);
            ah[5] = (_Float16)x5; al[5] = (_Float16)(x5 - (float)ah[5]);
            ah[6] = (_Float16)x6; al[6] = (_Float16)(x6 - (float)ah[6]);
            ah[7] = (_Float16)x7; al[7] = (_Float16)(x7 - (float)ah[7]);
            int c0 = cw + lr;
            f16x8 bh0 = *(const f16x8*)&wh[c0 * 128 + kb];
            f16x8 bl0 = *(const f16x8*)&wl[c0 * 128 + kb];
            f16x8 bh1 = *(const f16x8*)&wh[(c0 + 16) * 128 + kb];
            f16x8 bl1 = *(const f16x8*)&wl[(c0 + 16) * 128 + kb];
            acc0 = __builtin_amdgcn_mfma_f32_16x16x32_f16(ah, bh0, acc0, 0, 0, 0);
            acc1 = __builtin_amdgcn_mfma_f32_16x16x32_f16(ah, bh1, acc1, 0, 0, 0);
            acc0 = __builtin_amdgcn_mfma_f32_16x16x32_f16(al, bh0, acc0, 0, 0, 0);
            acc1 = __builtin_amdgcn_mfma_f32_16x16x32_f16(al, bh1, acc1, 0, 0, 0);
            acc0 = __builtin_amdgcn_mfma_f32_16x16x32_f16(ah, bl0, acc0, 0, 0, 0);
            acc1 = __builtin_amdgcn_mfma_f32_16x16x32_f16(ah, bl1, acc1, 0, 0, 0);
        }
#pragma unroll
        for (int reg = 0; reg < 4; reg++) {
            int r = rw + lg * 4 + reg;
            int c = cw + lr;
            if (r < NN) {
                float d = rsqrtf((float)deg[r] + 1.0f);
                g16[r * 128 + c] = __float2half(acc0[reg] * d);
                g16[r * 128 + c + 16] = __float2half(acc1[reg] * d);
            } else {  // zero pad rows 10000..10015
                g16[r * 128 + c] = __float2half(0.f);
                g16[r * 128 + c + 16] = __float2half(0.f);
            }
        }
    }
}

// ---------------- aggregation phase: dual-edge half-wave ----------------
__device__ __forceinline__ void accp(uint2 v, float2& p, float2& q) {
    float2 f0 = __half22float2(*(__half2*)&v.x);
    float2 f1 = __half22float2(*(__half2*)&v.y);
    p.x += f0.x; p.y += f0.y; q.x += f1.x; q.y += f1.y;
}

__device__ __forceinline__ void agg_phase(const __half* __restrict__ g16,
                                          const float* __restrict__ bias,
                                          const int* __restrict__ deg,
                                          const int* __restrict__ csrc,
                                          float* __restrict__ out,
                                          int bid, int t) {
    int w = t >> 6, l = t & 63;
    int half = l >> 5, li = l & 31;
    int co = li * 4;  // column offset in halfs
    for (int i = bid * 4 + w; i < NN; i += GRIDSZ * 4) {
        int dgi = __builtin_amdgcn_readfirstlane(deg[i]);
        int n = min(dgi, CAP - 1);
        int np = (n + 1) & ~1;  // even; slot n = pad when n odd
        float2 A0 = {0.f, 0.f}, A1 = {0.f, 0.f};
        float2 B0 = {0.f, 0.f}, B1 = {0.f, 0.f};
        if (half == 0) {  // self contribution
            uint2 sv = *(const uint2*)&g16[i * 128 + co];
            float2 f0 = __half22float2(*(__half2*)&sv.x);
            float2 f1 = __half22float2(*(__half2*)&sv.y);
            A0 = f0; A1 = f1;
        }
        const int* cp = &csrc[i << 7];
        for (int base = 0; base < np; base += 64) {
            int m = np - base;
            if (m > 64) m = 64;  // even
            int myedge = (l < m) ? cp[base + l] : NN;
            int pairs = m >> 1;
            int j = 0;
            for (; j + 8 <= pairs; j += 8) {
                int r0 = __shfl(myedge, 2 * j + half);
                int r1 = __shfl(myedge, 2 * j + 2 + half);
                int r2 = __shfl(myedge, 2 * j + 4 + half);
                int r3 = __shfl(myedge, 2 * j + 6 + half);
                int r4 = __shfl(myedge, 2 * j + 8 + half);
                int r5 = __shfl(myedge, 2 * j + 10 + half);
                int r6 = __shfl(myedge, 2 * j + 12 + half);
                int r7 = __shfl(myedge, 2 * j + 14 + half);
                uint2 v0 = *(const uint2*)&g16[r0 * 128 + co];
                uint2 v1 = *(const uint2*)&g16[r1 * 128 + co];
                uint2 v2 = *(const uint2*)&g16[r2 * 128 + co];
                uint2 v3 = *(const uint2*)&g16[r3 * 128 + co];
                uint2 v4 = *(const uint2*)&g16[r4 * 128 + co];
                uint2 v5 = *(const uint2*)&g16[r5 * 128 + co];
                uint2 v6 = *(const uint2*)&g16[r6 * 128 + co];
                uint2 v7 = *(const uint2*)&g16[r7 * 128 + co];
                accp(v0, A0, A1); accp(v1, B0, B1);
                accp(v2, A0, A1); accp(v3, B0, B1);
                accp(v4, A0, A1); accp(v5, B0, B1);
                accp(v6, A0, A1); accp(v7, B0, B1);
            }
            for (; j < pairs; j++) {
                int r = __shfl(myedge, 2 * j + half);
                uint2 v = *(const uint2*)&g16[r * 128 + co];
                accp(v, A0, A1);
            }
        }
        A0.x += B0.x; A0.y += B0.y; A1.x += B1.x; A1.y += B1.y;
        A0.x += __shfl_xor(A0.x, 32);
        A0.y += __shfl_xor(A0.y, 32);
        A1.x += __shfl_xor(A1.x, 32);
        A1.y += __shfl_xor(A1.y, 32);
        if (half == 0) {
            float di = rsqrtf((float)dgi + 1.0f);
            float4 bb = *(const float4*)&bias[co];
            float4 o;
            o.x = di * A0.x + bb.x;
            o.y = di * A0.y + bb.y;
            o.z = di * A1.x + bb.z;
            o.w = di * A1.y + bb.w;
            *(float4*)&out[i * 128 + co] = o;
        }
    }
}

// ---------------- the fused kernel ----------------
__global__ __launch_bounds__(256, 4) void k_fused(
    const float* __restrict__ x, const int* __restrict__ ei, const int* __restrict__ batch,
    const float* __restrict__ W0, const float* __restrict__ b0,
    const float* __restrict__ W1, const float* __restrict__ b1,
    const float* __restrict__ W2, const float* __restrict__ b2,
    float* __restrict__ out,
    int* deg, int* gstart, int* bcur, int* flags, int* go, int* csrc, __half* g16,
    float* abuf, int* pk, __half* wh, __half* wl)
{
    __shared__ ShMem sh;
    int bid = blockIdx.x, t = threadIdx.x;

    // ---- phase AB: gstart scan | W split | p1 coarse-bin (independent sub-jobs) ----
    if (bid < 40) {
        int i = bid * 256 + t;
        if (i < NN) {
            int b = batch[i];
            int prev = (i == 0) ? -1 : batch[i - 1];
            for (int g = prev + 1; g <= b; g++) gstart[g] = i;
            if (i == NN - 1)
                for (int g = b + 1; g <= NG; g++) gstart[g] = NN;
        }
    } else if (bid < 232) {
        int wid = bid - 40;             // 0..191
        int z = wid >> 6;               // which W
        int q = (wid & 63) * 256 + t;   // 0..16383
        int c = q >> 7, k = q & 127;
        const float* W = (z == 0) ? W0 : (z == 1) ? W1 : W2;
        float v = W[k * 128 + c];
        __half h = __float2half(v);
        __half lo = __float2half(v - __half2float(h));
        wh[z * 16384 + c * 128 + k] = h;   // transposed [c][k]
        wl[z * 16384 + c * 128 + k] = lo;
    } else if (bid < 389) {
        // p1: bins edges into pk[bucket*BCAP + slot] = src | ((dst&15)<<14)
        for (int q = t; q < NB; q += 256) sh.hist[q] = 0;
        __syncthreads();
        int4 s4[4], d4[4];
        int ebase = (bid - 232) * 4096;
#pragma unroll
        for (int q = 0; q < 4; q++) {
            int e = ebase + q * 1024 + t * 4;
            if (e < NE) {
                s4[q] = *(const int4*)&ei[e];
                d4[q] = *(const int4*)&ei[NE + e];
                atomicAdd(&sh.hist[d4[q].x >> 4], 1);
                atomicAdd(&sh.hist[d4[q].y >> 4], 1);
                atomicAdd(&sh.hist[d4[q].z >> 4], 1);
                atomicAdd(&sh.hist[d4[q].w >> 4], 1);
            }
        }
        __syncthreads();
        for (int q = t; q < NB; q += 256) {
            int h = sh.hist[q];
            sh.hist[q] = (h > 0) ? atomicAdd(&bcur[q], h) : 0;
        }
        __syncthreads();
#pragma unroll
        for (int q = 0; q < 4; q++) {
            int e = ebase + q * 1024 + t * 4;
            if (e < NE) {
                int b0i = d4[q].x >> 4, b1i = d4[q].y >> 4, b2i = d4[q].z >> 4, b3i = d4[q].w >> 4;
                int r0 = atomicAdd(&sh.hist[b0i], 1);
                int r1 = atomicAdd(&sh.hist[b1i], 1);
                int r2 = atomicAdd(&sh.hist[b2i], 1);
                int r3 = atomicAdd(&sh.hist[b3i], 1);
                if (r0 < BCAP) pk[b0i * BCAP + r0] = s4[q].x | ((d4[q].x & 15) << 14);
                if (r1 < BCAP) pk[b1i * BCAP + r1] = s4[q].y | ((d4[q].y & 15) << 14);
                if (r2 < BCAP) pk[b2i * BCAP + r2] = s4[q].z | ((d4[q].z & 15) << 14);
                if (r3 < BCAP) pk[b3i * BCAP + r3] = s4[q].w | ((d4[q].w & 15) << 14);
            }
        }
    }
    gsync(flags, go, 0, bid, t);

    // ---- phase C: p2 fine CSR (blocks 0..624) ----
    if (bid < NB) {
        if (t < 16) sh.p2.cnt[t] = 0;
        __syncthreads();
        int n = bcur[bid];
        if (n > BCAP) n = BCAP;
        const int* pb = &pk[bid * BCAP];
        for (int i = t; i < n; i += 256) {
            int v = pb[i];
            int nd = v >> 14;
            int slot = atomicAdd(&sh.p2.cnt[nd], 1);
            if (slot < CAP) sh.p2.buf[(nd << 7) + slot] = v & 0x3FFF;
        }
        __syncthreads();
        int node0 = bid << 4;
        if (t < 16) {
            int c = sh.p2.cnt[t];
            deg[node0 + t] = c;
            sh.p2.buf[(t << 7) + min(c, CAP - 1)] = NN;  // pad -> zero row
        }
        __syncthreads();
        int4* d4 = (int4*)&csrc[node0 << 7];
        const int4* s4 = (const int4*)sh.p2.buf;
#pragma unroll
        for (int i = 0; i < 2; i++) d4[t + i * 256] = s4[t + i * 256];
    }
    gsync(flags, go, 1, bid, t);

    // ---- layers ----
    gemm_phase(x, wh, wl, deg, g16, 0, bid, t);
    gsync(flags, go, 2, bid, t);
    agg_phase(g16, b0, deg, csrc, abuf, bid, t);
    gsync(flags, go, 3, bid, t);
    gemm_phase(abuf, wh + 16384, wl + 16384, deg, g16, 1, bid, t);
    gsync(flags, go, 4, bid, t);
    agg_phase(g16, b1, deg, csrc, abuf, bid, t);
    gsync(flags, go, 5, bid, t);
    gemm_phase(abuf, wh + 32768, wl + 32768, deg, g16, 1, bid, t);
    gsync(flags, go, 6, bid, t);
    agg_phase(g16, b2, deg, csrc, abuf, bid, t);
    gsync(flags, go, 7, bid, t);

    // ---- tail: mean pool (blocks 0..63) ----
    if (bid < NG) {
        int g = bid;
        int s = gstart[g], e = gstart[g + 1];
        int c = t & 127, hf = t >> 7;
        float acc = 0.f;
        for (int n = s + hf; n < e; n += 2) acc += abuf[n * 128 + c];
        sh.sm[t] = acc;
        __syncthreads();
        if (hf == 0) {
            float cnt = (float)max(e - s, 1);
            out[g * 128 + c] = (sh.sm[c] + sh.sm[128 + c]) / cnt;
        }
    }
}

extern "C" void kernel_launch(void* const* d_in, const int* in_sizes, int n_in,
                              void* d_out, int out_size, void* d_ws, size_t ws_size,
                              hipStream_t stream) {
    const float* x     = (const float*)d_in[0];
    const int*   ei    = (const int*)d_in[1];
    const int*   batch = (const int*)d_in[2];
    const float* W0 = (const float*)d_in[3];
    const float* b0 = (const float*)d_in[4];
    const float* W1 = (const float*)d_in[5];
    const float* b1 = (const float*)d_in[6];
    const float* W2 = (const float*)d_in[7];
    const float* b2 = (const float*)d_in[8];
    float* out = (float*)d_out;

    // workspace layout (float units)
    float* ws    = (float*)d_ws;
    int*   deg   = (int*)ws;                   // 10000 ints
    int*   gstart= (int*)(ws + 10240);         // 65 ints
    int*   flags = (int*)(ws + 10320);         // 1024 ints  -- memset'd
    int*   go    = (int*)(ws + 11344);         // 16 ints    -- memset'd
    int*   bcur  = (int*)(ws + 11360);         // 640 ints   -- memset'd
    int*   csrc  = (int*)(ws + 12000);         // 10000*128 ints (5.12 MB)
    __half* g16  = (__half*)(ws + 1292000);    // 10016*128 fp16 (incl. 16 zero pad rows)
    float* abuf  = ws + 1933024;               // 10000*128 f32 (5.12 MB)
    int*   pk    = (int*)(ws + 1933024);       // NB*BCAP ints (3.2 MB) — aliases abuf (dead before agg0)
    __half* wh   = (__half*)(ws + 3213024);    // 3*128*128 fp16 hi, [c][k]
    __half* wlo  = (__half*)(ws + 3237600);    // 3*128*128 fp16 lo

    hipMemsetAsync(ws + 10320, 0, (1024 + 16 + 640) * sizeof(int), stream);  // flags+go+bcur
    k_fused<<<GRIDSZ, 256, 0, stream>>>(
        x, ei, batch, W0, b0, W1, b1, W2, b2, out,
        deg, gstart, bcur, flags, go, csrc, g16, abuf, pk, wh, wlo);
}

// Round 11
// 184.690 us; speedup vs baseline: 6.4142x; 5.4594x over previous
//
#include <hip/hip_runtime.h>
#include <hip/hip_fp16.h>

// GCN: merged pipeline, 6 kernels + 1 memset.
//   memset(bcur) | k_initp1 (gstart|Wsplit|p1|pads) | k_p2g0 (CSR + gemm0)
//   | k_ag x2 (agg_L + gemm_{L+1} via LDS row-tile) | k_agg (final agg) | k_pool
#define NN 10000
#define NE 640000
#define NG 64
#define CAP 128   // slot capacity per dst (slot deg holds zero-row pad)
#define NB 625    // buckets of 16 dst nodes
#define BCAP 1280 // per-bucket edge capacity

typedef _Float16 f16x8 __attribute__((ext_vector_type(8)));
typedef float f32x4 __attribute__((ext_vector_type(4)));

// split fp32 -> fp16 hi + fp16 residual (h ~ f32 accuracy via 3-term MFMA)
__device__ __forceinline__ void split8v(float4 xa, float4 xb, f16x8& ah, f16x8& al) {
    float x[8] = {xa.x, xa.y, xa.z, xa.w, xb.x, xb.y, xb.z, xb.w};
#pragma unroll
    for (int j = 0; j < 8; j++) {
        ah[j] = (_Float16)x[j];
        al[j] = (_Float16)(x[j] - (float)ah[j]);
    }
}

// ---------------- init + p1: gstart | W split | coarse-bin | g16 pad zero ----------------
__global__ __launch_bounds__(256) void k_initp1(
    const int* __restrict__ batch, int* __restrict__ gstart,
    const float* __restrict__ W0, const float* __restrict__ W1, const float* __restrict__ W2,
    __half* __restrict__ wh, __half* __restrict__ wl,
    const int* __restrict__ ei, int* __restrict__ bcur, int* __restrict__ pk,
    __half* __restrict__ g16a, __half* __restrict__ g16b)
{
    __shared__ int hist[NB];
    int bid = blockIdx.x, t = threadIdx.x;
    if (bid < 40) {
        int i = bid * 256 + t;
        if (i < NN) {
            int b = batch[i];
            int prev = (i == 0) ? -1 : batch[i - 1];
            for (int g = prev + 1; g <= b; g++) gstart[g] = i;
            if (i == NN - 1)
                for (int g = b + 1; g <= NG; g++) gstart[g] = NN;
        }
    } else if (bid < 232) {
        int wid = bid - 40;             // 0..191
        int z = wid >> 6;               // which W
        int q = (wid & 63) * 256 + t;   // 0..16383
        int c = q >> 7, k = q & 127;
        const float* W = (z == 0) ? W0 : (z == 1) ? W1 : W2;
        float v = W[k * 128 + c];
        __half h = __float2half(v);
        __half lo = __float2half(v - __half2float(h));
        wh[z * 16384 + c * 128 + k] = h;   // transposed [c][k]
        wl[z * 16384 + c * 128 + k] = lo;
    } else if (bid < 389) {
        // p1: pk[bucket*BCAP + slot] = src | ((dst&15)<<14)
        for (int q = t; q < NB; q += 256) hist[q] = 0;
        __syncthreads();
        int4 s4[4], d4[4];
        int ebase = (bid - 232) * 4096;
#pragma unroll
        for (int q = 0; q < 4; q++) {
            int e = ebase + q * 1024 + t * 4;
            if (e < NE) {
                s4[q] = *(const int4*)&ei[e];
                d4[q] = *(const int4*)&ei[NE + e];
                atomicAdd(&hist[d4[q].x >> 4], 1);
                atomicAdd(&hist[d4[q].y >> 4], 1);
                atomicAdd(&hist[d4[q].z >> 4], 1);
                atomicAdd(&hist[d4[q].w >> 4], 1);
            }
        }
        __syncthreads();
        for (int q = t; q < NB; q += 256) {
            int h = hist[q];
            hist[q] = (h > 0) ? atomicAdd(&bcur[q], h) : 0;
        }
        __syncthreads();
#pragma unroll
        for (int q = 0; q < 4; q++) {
            int e = ebase + q * 1024 + t * 4;
            if (e < NE) {
                int b0i = d4[q].x >> 4, b1i = d4[q].y >> 4, b2i = d4[q].z >> 4, b3i = d4[q].w >> 4;
                int r0 = atomicAdd(&hist[b0i], 1);
                int r1 = atomicAdd(&hist[b1i], 1);
                int r2 = atomicAdd(&hist[b2i], 1);
                int r3 = atomicAdd(&hist[b3i], 1);
                if (r0 < BCAP) pk[b0i * BCAP + r0] = s4[q].x | ((d4[q].x & 15) << 14);
                if (r1 < BCAP) pk[b1i * BCAP + r1] = s4[q].y | ((d4[q].y & 15) << 14);
                if (r2 < BCAP) pk[b2i * BCAP + r2] = s4[q].z | ((d4[q].z & 15) << 14);
                if (r3 < BCAP) pk[b3i * BCAP + r3] = s4[q].w | ((d4[q].w & 15) << 14);
            }
        }
    } else {
        // zero pad rows 10000..10015 of both g16 buffers (4096 B each = 256 uint4)
        uint4 z = {0u, 0u, 0u, 0u};
        ((uint4*)(g16a + NN * 128))[t] = z;
        ((uint4*)(g16b + NN * 128))[t] = z;
    }
}

// ---------------- p2 + gemm layer 0: fine CSR, then 16x128 MFMA tile (rows = own nodes) ----------------
__global__ __launch_bounds__(512) void k_p2g0(
    const int* __restrict__ bcur, const int* __restrict__ pk,
    const float* __restrict__ x,
    const __half* __restrict__ whT, const __half* __restrict__ wlT,
    int* __restrict__ deg, int* __restrict__ csrc, __half* __restrict__ g16a)
{
    __shared__ int buf[16 * CAP];  // 8 KB
    __shared__ int cnt[16];
    int b = blockIdx.x, t = threadIdx.x;
    if (t < 16) cnt[t] = 0;
    __syncthreads();

    int n = bcur[b];
    if (n > BCAP) n = BCAP;
    const int* pb = &pk[b * BCAP];
    for (int i = t; i < n; i += 512) {
        int v = pb[i];
        int nd = v >> 14;
        int slot = atomicAdd(&cnt[nd], 1);
        if (slot < CAP) buf[(nd << 7) + slot] = v & 0x3FFF;
    }
    __syncthreads();

    int node0 = b << 4;
    if (t < 16) {
        int c = cnt[t];
        deg[node0 + t] = c;
        buf[(t << 7) + min(c, CAP - 1)] = NN;  // pad -> zero row
    }
    __syncthreads();

    ((int4*)&csrc[node0 << 7])[t] = ((const int4*)buf)[t];  // 512 int4 = full bucket

    // ---- gemm layer 0: rows node0..node0+15, wave w covers cols w*16..w*16+15 ----
    int w = t >> 6, l = t & 63, lr = l & 15, lg = l >> 4;
    int cw = w * 16;
    const _Float16* whp = (const _Float16*)whT;
    const _Float16* wlp = (const _Float16*)wlT;
    f32x4 acc = {0.f, 0.f, 0.f, 0.f};
#pragma unroll
    for (int ks = 0; ks < 4; ks++) {
        int kb = ks * 32 + lg * 8;
        f16x8 ah, al;
        split8v(*(const float4*)&x[(node0 + lr) * 128 + kb],
                *(const float4*)&x[(node0 + lr) * 128 + kb + 4], ah, al);
        int c0 = cw + lr;
        f16x8 bh = *(const f16x8*)&whp[c0 * 128 + kb];
        f16x8 bl = *(const f16x8*)&wlp[c0 * 128 + kb];
        acc = __builtin_amdgcn_mfma_f32_16x16x32_f16(ah, bh, acc, 0, 0, 0);
        acc = __builtin_amdgcn_mfma_f32_16x16x32_f16(al, bh, acc, 0, 0, 0);
        acc = __builtin_amdgcn_mfma_f32_16x16x32_f16(ah, bl, acc, 0, 0, 0);
    }
#pragma unroll
    for (int reg = 0; reg < 4; reg++) {
        int row = lg * 4 + reg;
        float d = rsqrtf((float)cnt[row] + 1.0f);
        g16a[(node0 + row) * 128 + cw + lr] = __float2half(acc[reg] * d);
    }
}

// ---------------- agg layer L + gemm layer L+1 (LDS row-tile bridge) ----------------
__device__ __forceinline__ void accp(uint2 v, float2& p, float2& q) {
    float2 f0 = __half22float2(*(__half2*)&v.x);
    float2 f1 = __half22float2(*(__half2*)&v.y);
    p.x += f0.x; p.y += f0.y; q.x += f1.x; q.y += f1.y;
}

__global__ __launch_bounds__(512) void k_ag(
    const __half* __restrict__ gin, const float* __restrict__ bias,
    const int* __restrict__ deg, const int* __restrict__ csrc,
    const __half* __restrict__ whT, const __half* __restrict__ wlT,
    __half* __restrict__ gout)
{
    __shared__ float Xs[16][132];  // +4 pad: conflict-free column reads
    int base = blockIdx.x << 4;
    int t = threadIdx.x;
    int w = t >> 6, l = t & 63;
    int half = l >> 5, li = l & 31;
    int co = li * 4;
#pragma unroll
    for (int k4 = 0; k4 < 2; k4++) {
        int row = w * 2 + k4;
        int i = base + row;
        int dgi = __builtin_amdgcn_readfirstlane(deg[i]);
        int nn_ = min(dgi, CAP - 1);
        int np = (nn_ + 1) & ~1;  // even; slot nn_ = pad when odd
        float2 A0 = {0.f, 0.f}, A1 = {0.f, 0.f};
        float2 B0 = {0.f, 0.f}, B1 = {0.f, 0.f};
        if (half == 0) {  // self contribution
            uint2 sv = *(const uint2*)&gin[i * 128 + co];
            A0 = __half22float2(*(__half2*)&sv.x);
            A1 = __half22float2(*(__half2*)&sv.y);
        }
        const int* cp = &csrc[i << 7];
        for (int bs = 0; bs < np; bs += 64) {
            int m = np - bs;
            if (m > 64) m = 64;  // even
            int myedge = (l < m) ? cp[bs + l] : NN;
            int pairs = m >> 1;
            int j = 0;
            for (; j + 8 <= pairs; j += 8) {
                int r0 = __shfl(myedge, 2 * j + half);
                int r1 = __shfl(myedge, 2 * j + 2 + half);
                int r2 = __shfl(myedge, 2 * j + 4 + half);
                int r3 = __shfl(myedge, 2 * j + 6 + half);
                int r4 = __shfl(myedge, 2 * j + 8 + half);
                int r5 = __shfl(myedge, 2 * j + 10 + half);
                int r6 = __shfl(myedge, 2 * j + 12 + half);
                int r7 = __shfl(myedge, 2 * j + 14 + half);
                uint2 v0 = *(const uint2*)&gin[r0 * 128 + co];
                uint2 v1 = *(const uint2*)&gin[r1 * 128 + co];
                uint2 v2 = *(const uint2*)&gin[r2 * 128 + co];
                uint2 v3 = *(const uint2*)&gin[r3 * 128 + co];
                uint2 v4 = *(const uint2*)&gin[r4 * 128 + co];
                uint2 v5 = *(const uint2*)&gin[r5 * 128 + co];
                uint2 v6 = *(const uint2*)&gin[r6 * 128 + co];
                uint2 v7 = *(const uint2*)&gin[r7 * 128 + co];
                accp(v0, A0, A1); accp(v1, B0, B1);
                accp(v2, A0, A1); accp(v3, B0, B1);
                accp(v4, A0, A1); accp(v5, B0, B1);
                accp(v6, A0, A1); accp(v7, B0, B1);
            }
            for (; j < pairs; j++) {
                int r = __shfl(myedge, 2 * j + half);
                uint2 v = *(const uint2*)&gin[r * 128 + co];
                accp(v, A0, A1);
            }
        }
        A0.x += B0.x; A0.y += B0.y; A1.x += B1.x; A1.y += B1.y;
        A0.x += __shfl_xor(A0.x, 32);
        A0.y += __shfl_xor(A0.y, 32);
        A1.x += __shfl_xor(A1.x, 32);
        A1.y += __shfl_xor(A1.y, 32);
        if (half == 0) {  // bias + relu, stage gemm input row in LDS
            float di = rsqrtf((float)dgi + 1.0f);
            float4 bb = *(const float4*)&bias[co];
            float4 o;
            o.x = fmaxf(di * A0.x + bb.x, 0.f);
            o.y = fmaxf(di * A0.y + bb.y, 0.f);
            o.z = fmaxf(di * A1.x + bb.z, 0.f);
            o.w = fmaxf(di * A1.y + bb.w, 0.f);
            *(float4*)&Xs[row][co] = o;
        }
    }
    __syncthreads();

    // ---- gemm layer L+1: rows base..base+15 from LDS, wave w covers cols w*16.. ----
    int lr = l & 15, lg = l >> 4;
    int cw = w * 16;
    const _Float16* whp = (const _Float16*)whT;
    const _Float16* wlp = (const _Float16*)wlT;
    f32x4 acc = {0.f, 0.f, 0.f, 0.f};
#pragma unroll
    for (int ks = 0; ks < 4; ks++) {
        int kb = ks * 32 + lg * 8;
        f16x8 ah, al;
        split8v(*(const float4*)&Xs[lr][kb], *(const float4*)&Xs[lr][kb + 4], ah, al);
        int c0 = cw + lr;
        f16x8 bh = *(const f16x8*)&whp[c0 * 128 + kb];
        f16x8 bl = *(const f16x8*)&wlp[c0 * 128 + kb];
        acc = __builtin_amdgcn_mfma_f32_16x16x32_f16(ah, bh, acc, 0, 0, 0);
        acc = __builtin_amdgcn_mfma_f32_16x16x32_f16(al, bh, acc, 0, 0, 0);
        acc = __builtin_amdgcn_mfma_f32_16x16x32_f16(ah, bl, acc, 0, 0, 0);
    }
#pragma unroll
    for (int reg = 0; reg < 4; reg++) {
        int row = lg * 4 + reg;
        float d = rsqrtf((float)deg[base + row] + 1.0f);
        gout[(base + row) * 128 + cw + lr] = __float2half(acc[reg] * d);
    }
}

// ---------------- final aggregation (layer 2): R5-proven dual-edge half-wave ----------------
__global__ __launch_bounds__(256) void k_agg(const __half* __restrict__ g16,
                                             const float* __restrict__ bias,
                                             const int* __restrict__ deg,
                                             const int* __restrict__ csrc,
                                             float* __restrict__ out) {
    int wid = blockIdx.x * 4 + (threadIdx.x >> 6);
    int l = threadIdx.x & 63;
    if (wid >= NN) return;
    int i = wid;
    int dgi = __builtin_amdgcn_readfirstlane(deg[i]);
    int n = min(dgi, CAP - 1);
    int np = (n + 1) & ~1;
    int half = l >> 5, li = l & 31;
    int co = li * 4;
    float2 A0 = {0.f, 0.f}, A1 = {0.f, 0.f};
    float2 B0 = {0.f, 0.f}, B1 = {0.f, 0.f};
    if (half == 0) {
        uint2 sv = *(const uint2*)&g16[i * 128 + co];
        A0 = __half22float2(*(__half2*)&sv.x);
        A1 = __half22float2(*(__half2*)&sv.y);
    }
    const int* cp = &csrc[i << 7];
    for (int base = 0; base < np; base += 64) {
        int m = np - base;
        if (m > 64) m = 64;
        int myedge = (l < m) ? cp[base + l] : NN;
        int pairs = m >> 1;
        int j = 0;
        for (; j + 8 <= pairs; j += 8) {
            int r0 = __shfl(myedge, 2 * j + half);
            int r1 = __shfl(myedge, 2 * j + 2 + half);
            int r2 = __shfl(myedge, 2 * j + 4 + half);
            int r3 = __shfl(myedge, 2 * j + 6 + half);
            int r4 = __shfl(myedge, 2 * j + 8 + half);
            int r5 = __shfl(myedge, 2 * j + 10 + half);
            int r6 = __shfl(myedge, 2 * j + 12 + half);
            int r7 = __shfl(myedge, 2 * j + 14 + half);
            uint2 v0 = *(const uint2*)&g16[r0 * 128 + co];
            uint2 v1 = *(const uint2*)&g16[r1 * 128 + co];
            uint2 v2 = *(const uint2*)&g16[r2 * 128 + co];
            uint2 v3 = *(const uint2*)&g16[r3 * 128 + co];
            uint2 v4 = *(const uint2*)&g16[r4 * 128 + co];
            uint2 v5 = *(const uint2*)&g16[r5 * 128 + co];
            uint2 v6 = *(const uint2*)&g16[r6 * 128 + co];
            uint2 v7 = *(const uint2*)&g16[r7 * 128 + co];
            accp(v0, A0, A1); accp(v1, B0, B1);
            accp(v2, A0, A1); accp(v3, B0, B1);
            accp(v4, A0, A1); accp(v5, B0, B1);
            accp(v6, A0, A1); accp(v7, B0, B1);
        }
        for (; j < pairs; j++) {
            int r = __shfl(myedge, 2 * j + half);
            uint2 v = *(const uint2*)&g16[r * 128 + co];
            accp(v, A0, A1);
        }
    }
    A0.x += B0.x; A0.y += B0.y; A1.x += B1.x; A1.y += B1.y;
    A0.x += __shfl_xor(A0.x, 32);
    A0.y += __shfl_xor(A0.y, 32);
    A1.x += __shfl_xor(A1.x, 32);
    A1.y += __shfl_xor(A1.y, 32);
    if (half == 0) {
        float di = rsqrtf((float)dgi + 1.0f);
        float4 bb = *(const float4*)&bias[co];
        float4 o;
        o.x = di * A0.x + bb.x;
        o.y = di * A0.y + bb.y;
        o.z = di * A1.x + bb.z;
        o.w = di * A1.y + bb.w;
        *(float4*)&out[i * 128 + co] = o;
    }
}

// ---------------- mean pool ----------------
__global__ __launch_bounds__(256) void k_pool(const float* __restrict__ h,
                                              const int* __restrict__ gstart,
                                              float* __restrict__ out) {
    int g = blockIdx.x;
    int s = gstart[g], e = gstart[g + 1];
    int t = threadIdx.x;
    int c = t & 127, half = t >> 7;
    float acc = 0.f;
    for (int n = s + half; n < e; n += 2) acc += h[n * 128 + c];
    __shared__ float sm[256];
    sm[t] = acc;
    __syncthreads();
    if (half == 0) {
        float cnt = (float)max(e - s, 1);
        out[g * 128 + c] = (sm[c] + sm[128 + c]) / cnt;
    }
}

extern "C" void kernel_launch(void* const* d_in, const int* in_sizes, int n_in,
                              void* d_out, int out_size, void* d_ws, size_t ws_size,
                              hipStream_t stream) {
    const float* x     = (const float*)d_in[0];
    const int*   ei    = (const int*)d_in[1];
    const int*   batch = (const int*)d_in[2];
    const float* W0 = (const float*)d_in[3];
    const float* b0 = (const float*)d_in[4];
    const float* W1 = (const float*)d_in[5];
    const float* b1 = (const float*)d_in[6];
    const float* W2 = (const float*)d_in[7];
    const float* b2 = (const float*)d_in[8];
    float* out = (float*)d_out;

    // workspace layout (float units)
    float* ws    = (float*)d_ws;
    int*   deg   = (int*)ws;                   // 10000 ints
    int*   gstart= (int*)(ws + 10240);         // 65 ints
    int*   bcur  = (int*)(ws + 10320);         // 625 ints -- memset'd
    int*   csrc  = (int*)(ws + 10960);         // 10000*128 ints (5.12 MB)
    __half* g16a = (__half*)(ws + 1290960);    // 10016*128 fp16 (incl. pad rows)
    __half* g16b = (__half*)(ws + 1931984);    // 10016*128 fp16 (incl. pad rows)
    float* abuf  = ws + 2573008;               // 10000*128 f32 (5.12 MB)
    int*   pk    = (int*)(ws + 2573008);       // NB*BCAP ints (3.2 MB) — aliases abuf (dead until final agg)
    __half* wh   = (__half*)(ws + 3853008);    // 3*128*128 fp16 hi, [c][k]
    __half* wlo  = (__half*)(ws + 3877584);    // 3*128*128 fp16 lo

    hipMemsetAsync(bcur, 0, 640 * sizeof(int), stream);
    k_initp1<<<390, 256, 0, stream>>>(batch, gstart, W0, W1, W2, wh, wlo, ei, bcur, pk,
                                      g16a, g16b);
    k_p2g0<<<NB, 512, 0, stream>>>(bcur, pk, x, wh, wlo, deg, csrc, g16a);
    k_ag<<<NB, 512, 0, stream>>>(g16a, b0, deg, csrc, wh + 16384, wlo + 16384, g16b);
    k_ag<<<NB, 512, 0, stream>>>(g16b, b1, deg, csrc, wh + 32768, wlo + 32768, g16a);
    k_agg<<<2500, 256, 0, stream>>>(g16a, b2, deg, csrc, abuf);
    k_pool<<<NG, 256, 0, stream>>>(abuf, gstart, out);
}